// Round 9
// baseline (469.144 us; speedup 1.0000x reference)
//
#include <hip/hip_runtime.h>
#include <math.h>

namespace {

typedef short short8 __attribute__((ext_vector_type(8)));
typedef float f32x16 __attribute__((ext_vector_type(16)));
typedef unsigned int u32;

constexpr int NEX = 256, LLEN = 2048, FEATS = 8192;
constexpr int PL = 512;          // 4*Dmax zeros on the left
constexpr int XSZ = 4096;

// packed bf16 split: (lo_bf16 << 16) | hi_bf16, both RNE
__device__ __forceinline__ u32 bfsplit(float x) {
  u32 b = __float_as_uint(x);
  u32 hb = (b + 0x7fffu + ((b >> 16) & 1u)) >> 16;
  float lo = x - __uint_as_float(hb << 16);
  u32 b2 = __float_as_uint(lo);
  u32 lb = (b2 + 0x7fffu + ((b2 >> 16) & 1u)) >> 16;
  return hb | (lb << 16);
}

// guaranteed single-instruction 3-input max/min
__device__ __forceinline__ float max3(float a, float b, float c) {
  float d;
  asm("v_max3_f32 %0, %1, %2, %3" : "=v"(d) : "v"(a), "v"(b), "v"(c));
  return d;
}
__device__ __forceinline__ float min3(float a, float b, float c) {
  float d;
  asm("v_min3_f32 %0, %1, %2, %3" : "=v"(d) : "v"(a), "v"(b), "v"(c));
  return d;
}
// 4-instruction 8-way trees
__device__ __forceinline__ float max8(const f32x16& c, int o) {
  float m0 = max3(c[o+0], c[o+1], c[o+2]);
  float m1 = max3(c[o+3], c[o+4], c[o+5]);
  float m2 = max3(c[o+6], c[o+7], m0);
  return fmaxf(m1, m2);
}
__device__ __forceinline__ float min8(const f32x16& c, int o) {
  float m0 = min3(c[o+0], c[o+1], c[o+2]);
  float m1 = min3(c[o+3], c[o+4], c[o+5]);
  float m2 = min3(c[o+6], c[o+7], m0);
  return fminf(m1, m2);
}

// count += (a == b) via vcc carry: 2 VALU instead of cmp+cndmask+add.
__device__ __forceinline__ void cnt_eq(u32& acc, float a, float b, u32 vz) {
  asm("v_cmp_eq_f32 vcc, %1, %2\n\t"
      "v_addc_co_u32 %0, vcc, %0, %3, vcc"
      : "+v"(acc) : "v"(a), "v"(b), "v"(vz) : "vcc");
}

#define MFMA __builtin_amdgcn_mfma_f32_32x32x16_bf16

template<int D, int DI>
__device__ __forceinline__ void body(
    const float* __restrict__ X, const float* __restrict__ W,
    float* __restrict__ out, u32* xhl, float* scratch, float* fin)
{
  const int n = blockIdx.x, diff = blockIdx.y, tid = threadIdx.x;
  const int lane = tid & 63, wave = tid >> 6;
  const int col = lane & 31, hi = lane >> 5;

  // ---- stage padded input as packed bf16 hi/lo (diff on the fly) ----
  const float* xr = X + n * LLEN;
  for (int i = tid; i < XSZ; i += 256) {
    float x = 0.f;
    if (diff) { if (i >= PL && i < PL + LLEN - 1) x = xr[i - PL + 1] - xr[i - PL]; }
    else      { if (i >= PL && i < PL + LLEN)     x = xr[i - PL]; }
    xhl[i] = bfsplit(x);
  }
  __syncthreads();

  const float* wall = W + (DI * 2 + diff) * (256 * 9);

  // Permuted A-row -> kernel map so each lane owns two complete 8-k groups:
  // row r holds kernel g*8+k, g = 2*(r>>4)+((r>>2)&1), k = (r&3)+4*((r>>3)&1).
  // Then c[0..7] = all 8 k of one group, c[8..15] = another full group.
  const int g_of_r = ((col >> 4) << 1) | ((col >> 2) & 1);
  const int k_of_r = (col & 3) | (((col >> 3) & 1) << 2);
  const int kloc = g_of_r * 8 + k_of_r;

  float* sw = scratch + wave * 1024;   // per-wave [32][32] XOR-swizzled

  // Zero C operand pinned to AGPRs: write-once, MFMA reads C from AGPR
  // natively -> frees 16 arch VGPRs, no per-tile copies (unlike "+v" pin).
  f32x16 czero = {};
  asm("" : "+a"(czero));
  const u32 vz = 0;

  for (int kt2 = 0; kt2 < 2; ++kt2) {
    // A fragments for this 32-kern tile (taps padded 9->16 with zeros)
    short8 ah, al;
    {
      const float* wrow = wall + (wave * 64 + kt2 * 32 + kloc) * 9;
      #pragma unroll
      for (int e = 0; e < 8; ++e) {
        int j = hi * 8 + e;
        float wv = (j < 9) ? wrow[j] : 0.f;
        u32 p = bfsplit(wv);
        ah[e] = (short)(p & 0xffffu);
        al[e] = (short)(p >> 16);
      }
    }

    float accM[16];
    u32   accN[16];
    #pragma unroll
    for (int i = 0; i < 16; ++i) { accM[i] = 0.f; accN[i] = 0u; }

    // NO unroll: keeps live ranges of uu/bh/bl/c single -> fits 128-reg cap
    #pragma clang loop unroll_count(1)
    for (int tt = 0; tt < 64; ++tt) {
      // B fragment: B[j=8*hi+e][col] = x[tt*32 + col + (j-4)*D]
      const int ebase = PL + tt * 32 + col + (hi * 8 - 4) * D;
      u32 uu[8];
      #pragma unroll
      for (int e = 0; e < 8; ++e) uu[e] = xhl[ebase + e * D];
      union { short8 s; u32 u[4]; } bh, bl;
      #pragma unroll
      for (int p = 0; p < 4; ++p) {
        bh.u[p] = __builtin_amdgcn_perm(uu[2*p+1], uu[2*p], 0x05040100u);
        bl.u[p] = __builtin_amdgcn_perm(uu[2*p+1], uu[2*p], 0x07060302u);
      }

      // (wh+wl)(xh+xl) ~= wl*xh + wh*xl + wh*xh (lo*lo dropped)
      f32x16 c;
      c = MFMA(al, bh.s, czero, 0, 0, 0);
      c = MFMA(ah, bl.s, c,     0, 0, 0);
      c = MFMA(ah, bh.s, c,     0, 0, 0);

      const float zx0 = max8(c, 0), zn0 = min8(c, 0);
      const float zx1 = max8(c, 8), zn1 = min8(c, 8);
      #pragma unroll
      for (int i = 0; i < 8; ++i) {
        accM[i] += (c[i] == zx0) ? c[i] : 0.f;
        cnt_eq(accN[i], c[i], zn0, vz);
      }
      #pragma unroll
      for (int i = 8; i < 16; ++i) {
        accM[i] += (c[i] == zx1) ? c[i] : 0.f;
        cnt_eq(accN[i], c[i], zn1, vz);
      }
    }

    // ---- flush: wave-private XOR-swizzled transpose (no atomics/barrier) ----
    // acc index i of lane (col,hi) is local kern s = 8*hi + 16*(i>>3) + (i&7).
    float sM = 0.f, sN = 0.f;
    #pragma unroll
    for (int i = 0; i < 16; ++i) {
      int s = 8 * hi + 16 * (i >> 3) + (i & 7);
      sw[s * 32 + (col ^ s)] = accM[i];
    }
    if (lane < 32) {
      #pragma unroll
      for (int j = 0; j < 32; ++j) sM += sw[lane * 32 + (j ^ lane)];
    }
    #pragma unroll
    for (int i = 0; i < 16; ++i) {
      int s = 8 * hi + 16 * (i >> 3) + (i & 7);
      sw[s * 32 + (col ^ s)] = (float)accN[i];
    }
    if (lane < 32) {
      #pragma unroll
      for (int j = 0; j < 32; ++j) sN += sw[lane * 32 + (j ^ lane)];
      *(float2*)(fin + ((wave * 32 + lane) * 2 + kt2) * 2) = make_float2(sM, sN);
    }
  }
  __syncthreads();

  // ---- final: tid = kern (single owner, no cross-wave sum) ----
  const int w2 = tid >> 6, kt2f = (tid >> 5) & 1, r = tid & 31;
  float2 mn2 = *(const float2*)(fin + ((w2 * 32 + r) * 2 + kt2f) * 2);
  float M = mn2.x, N = mn2.y;

  if (diff) {
    // remove the spurious t=2047 column (diff branch has 2047 timesteps)
    const float* wrow = wall + tid * 9;
    float z = 0.f;
    #pragma unroll
    for (int j = 0; j < 9; ++j) {
      u32 u = xhl[PL + (LLEN - 1) + (j - 4) * D];
      float xh = __uint_as_float((u & 0xffffu) << 16);
      float xl = __uint_as_float((u >> 16) << 16);
      u32 wp = bfsplit(wrow[j]);
      float wh = __uint_as_float((wp & 0xffffu) << 16);
      float wl = __uint_as_float((wp >> 16) << 16);
      z += wh * xh + wh * xl + wl * xh;
    }
    float* zrow = scratch;
    zrow[tid] = z;
    __syncthreads();
    const int h8 = tid & ~7;
    float zxv = zrow[h8], znv = zrow[h8];
    #pragma unroll
    for (int j = 1; j < 8; ++j) {
      zxv = fmaxf(zxv, zrow[h8 + j]);
      znv = fminf(znv, zrow[h8 + j]);
    }
    M -= (z == zxv) ? z : 0.f;
    N -= (z == znv) ? 1.f : 0.f;
  }

  const int base = n * FEATS + (DI * 4 + diff * 2) * 256 + tid;
  out[base]       = M > 0.f ? sqrtf(M) : 0.f;    // count_max
  out[base + 256] = N > 0.f ? sqrtf(N) : 0.f;    // count_min
}

__global__ __launch_bounds__(256, 4) void hydra_kernel(
    const float* __restrict__ X, const float* __restrict__ W,
    float* __restrict__ out)
{
  __shared__ u32   xhl[XSZ];        // 16 KB packed bf16 hi|lo
  __shared__ float scratch[4096];   // 16 KB: 4 waves x [32][32]
  __shared__ float fin[512];        // 2 KB: [4][32][2]{M,N}
  switch (blockIdx.z) {
    case 0: body<1,   0>(X, W, out, xhl, scratch, fin); break;
    case 1: body<2,   1>(X, W, out, xhl, scratch, fin); break;
    case 2: body<4,   2>(X, W, out, xhl, scratch, fin); break;
    case 3: body<8,   3>(X, W, out, xhl, scratch, fin); break;
    case 4: body<16,  4>(X, W, out, xhl, scratch, fin); break;
    case 5: body<32,  5>(X, W, out, xhl, scratch, fin); break;
    case 6: body<64,  6>(X, W, out, xhl, scratch, fin); break;
    case 7: body<128, 7>(X, W, out, xhl, scratch, fin); break;
  }
}

} // namespace

extern "C" void kernel_launch(void* const* d_in, const int* in_sizes, int n_in,
                              void* d_out, int out_size, void* d_ws, size_t ws_size,
                              hipStream_t stream) {
  const float* X = (const float*)d_in[0];
  const float* W = (const float*)d_in[1];
  float* out = (float*)d_out;
  dim3 grid(NEX, 2, 8);
  hipLaunchKernelGGL(hydra_kernel, grid, dim3(256), 0, stream, X, W, out);
}

// Round 10
// 416.960 us; speedup vs baseline: 1.1252x; 1.1252x over previous
//
#include <hip/hip_runtime.h>
#include <math.h>

namespace {

typedef short short8 __attribute__((ext_vector_type(8)));
typedef float f32x16 __attribute__((ext_vector_type(16)));
typedef unsigned int u32;

constexpr int NEX = 256, LLEN = 2048, FEATS = 8192;
constexpr int PL = 512;          // 4*Dmax zeros on the left
constexpr int XSZ = 4096;

// packed bf16 split: (lo_bf16 << 16) | hi_bf16, both RNE
__device__ __forceinline__ u32 bfsplit(float x) {
  u32 b = __float_as_uint(x);
  u32 hb = (b + 0x7fffu + ((b >> 16) & 1u)) >> 16;
  float lo = x - __uint_as_float(hb << 16);
  u32 b2 = __float_as_uint(lo);
  u32 lb = (b2 + 0x7fffu + ((b2 >> 16) & 1u)) >> 16;
  return hb | (lb << 16);
}

// 4-instruction 8-way trees (compiler fuses fmaxf chains to v_max3)
__device__ __forceinline__ float max8(const f32x16& c, int o) {
  float m0 = fmaxf(fmaxf(c[o+0], c[o+1]), c[o+2]);
  float m1 = fmaxf(fmaxf(c[o+3], c[o+4]), c[o+5]);
  float m2 = fmaxf(c[o+6], c[o+7]);
  return fmaxf(fmaxf(m0, m1), m2);
}
__device__ __forceinline__ float min8(const f32x16& c, int o) {
  float m0 = fminf(fminf(c[o+0], c[o+1]), c[o+2]);
  float m1 = fminf(fminf(c[o+3], c[o+4]), c[o+5]);
  float m2 = fminf(c[o+6], c[o+7]);
  return fminf(fminf(m0, m1), m2);
}

// count += (a == b) via vcc carry: 2 VALU instead of cmp+cndmask+add.
__device__ __forceinline__ void cnt_eq(u32& acc, float a, float b, u32 vz) {
  asm("v_cmp_eq_f32 vcc, %1, %2\n\t"
      "v_addc_co_u32 %0, vcc, %0, %3, vcc"
      : "+v"(acc) : "v"(a), "v"(b), "v"(vz) : "vcc");
}

#define MFMA __builtin_amdgcn_mfma_f32_32x32x16_bf16

template<int D, int DI>
__device__ __forceinline__ void body(
    const float* __restrict__ X, const float* __restrict__ W,
    float* __restrict__ out, u32* xhl, float* scratch, float* fin)
{
  const int n = blockIdx.x, diff = blockIdx.y, tid = threadIdx.x;
  const int lane = tid & 63, wave = tid >> 6;
  const int col = lane & 31, hi = lane >> 5;

  // ---- stage padded input as packed bf16 hi/lo (diff on the fly) ----
  const float* xr = X + n * LLEN;
  for (int i = tid; i < XSZ; i += 256) {
    float x = 0.f;
    if (diff) { if (i >= PL && i < PL + LLEN - 1) x = xr[i - PL + 1] - xr[i - PL]; }
    else      { if (i >= PL && i < PL + LLEN)     x = xr[i - PL]; }
    xhl[i] = bfsplit(x);
  }
  __syncthreads();

  const float* wall = W + (DI * 2 + diff) * (256 * 9);

  // Permuted A-row -> kernel map so each lane owns two complete 8-k groups:
  // row r holds kernel g*8+k, g = 2*(r>>4)+((r>>2)&1), k = (r&3)+4*((r>>3)&1).
  // Then c[0..7] = all 8 k of one group, c[8..15] = another full group.
  const int g_of_r = ((col >> 4) << 1) | ((col >> 2) & 1);
  const int k_of_r = (col & 3) | (((col >> 3) & 1) << 2);
  const int kloc = g_of_r * 8 + k_of_r;

  float* sw = scratch + wave * 1024;   // per-wave [32][32] XOR-swizzled

  const f32x16 czero = {};             // hoisted zero C operand
  const u32 vz = 0;

  for (int kt2 = 0; kt2 < 2; ++kt2) {
    // A fragments for this 32-kern tile (taps padded 9->16 with zeros)
    short8 ah, al;
    {
      const float* wrow = wall + (wave * 64 + kt2 * 32 + kloc) * 9;
      #pragma unroll
      for (int e = 0; e < 8; ++e) {
        int j = hi * 8 + e;
        float wv = (j < 9) ? wrow[j] : 0.f;
        u32 p = bfsplit(wv);
        ah[e] = (short)(p & 0xffffu);
        al[e] = (short)(p >> 16);
      }
    }

    float accM[16];
    u32   accN[16];
    #pragma unroll
    for (int i = 0; i < 16; ++i) { accM[i] = 0.f; accN[i] = 0u; }

    // NO unroll: keeps live ranges of uu/bh/bl/c single
    #pragma clang loop unroll_count(1)
    for (int tt = 0; tt < 64; ++tt) {
      // B fragment: B[j=8*hi+e][col] = x[tt*32 + col + (j-4)*D]
      const int ebase = PL + tt * 32 + col + (hi * 8 - 4) * D;
      u32 uu[8];
      #pragma unroll
      for (int e = 0; e < 8; ++e) uu[e] = xhl[ebase + e * D];
      union { short8 s; u32 u[4]; } bh, bl;
      #pragma unroll
      for (int p = 0; p < 4; ++p) {
        bh.u[p] = __builtin_amdgcn_perm(uu[2*p+1], uu[2*p], 0x05040100u);
        bl.u[p] = __builtin_amdgcn_perm(uu[2*p+1], uu[2*p], 0x07060302u);
      }

      // (wh+wl)(xh+xl) ~= wl*xh + wh*xl + wh*xh (lo*lo dropped)
      f32x16 c;
      c = MFMA(al, bh.s, czero, 0, 0, 0);
      c = MFMA(ah, bl.s, c,     0, 0, 0);
      c = MFMA(ah, bh.s, c,     0, 0, 0);

      const float zx0 = max8(c, 0), zn0 = min8(c, 0);
      const float zx1 = max8(c, 8), zn1 = min8(c, 8);
      #pragma unroll
      for (int i = 0; i < 8; ++i) {
        accM[i] += (c[i] == zx0) ? c[i] : 0.f;
        cnt_eq(accN[i], c[i], zn0, vz);
      }
      #pragma unroll
      for (int i = 8; i < 16; ++i) {
        accM[i] += (c[i] == zx1) ? c[i] : 0.f;
        cnt_eq(accN[i], c[i], zn1, vz);
      }
    }

    // ---- flush: wave-private XOR-swizzled transpose (no atomics/barrier) ----
    // acc index i of lane (col,hi) is local kern s = 8*hi + 16*(i>>3) + (i&7).
    float sM = 0.f, sN = 0.f;
    #pragma unroll
    for (int i = 0; i < 16; ++i) {
      int s = 8 * hi + 16 * (i >> 3) + (i & 7);
      sw[s * 32 + (col ^ s)] = accM[i];
    }
    if (lane < 32) {
      #pragma unroll
      for (int j = 0; j < 32; ++j) sM += sw[lane * 32 + (j ^ lane)];
    }
    #pragma unroll
    for (int i = 0; i < 16; ++i) {
      int s = 8 * hi + 16 * (i >> 3) + (i & 7);
      sw[s * 32 + (col ^ s)] = (float)accN[i];
    }
    if (lane < 32) {
      #pragma unroll
      for (int j = 0; j < 32; ++j) sN += sw[lane * 32 + (j ^ lane)];
      *(float2*)(fin + ((wave * 32 + lane) * 2 + kt2) * 2) = make_float2(sM, sN);
    }
  }
  __syncthreads();

  // ---- final: tid = kern (single owner, no cross-wave sum) ----
  const int w2 = tid >> 6, kt2f = (tid >> 5) & 1, r = tid & 31;
  float2 mn2 = *(const float2*)(fin + ((w2 * 32 + r) * 2 + kt2f) * 2);
  float M = mn2.x, N = mn2.y;

  if (diff) {
    // remove the spurious t=2047 column (diff branch has 2047 timesteps)
    const float* wrow = wall + tid * 9;
    float z = 0.f;
    #pragma unroll
    for (int j = 0; j < 9; ++j) {
      u32 u = xhl[PL + (LLEN - 1) + (j - 4) * D];
      float xh = __uint_as_float((u & 0xffffu) << 16);
      float xl = __uint_as_float((u >> 16) << 16);
      u32 wp = bfsplit(wrow[j]);
      float wh = __uint_as_float((wp & 0xffffu) << 16);
      float wl = __uint_as_float((wp >> 16) << 16);
      z += wh * xh + wh * xl + wl * xh;
    }
    float* zrow = scratch;
    zrow[tid] = z;
    __syncthreads();
    const int h8 = tid & ~7;
    float zxv = zrow[h8], znv = zrow[h8];
    #pragma unroll
    for (int j = 1; j < 8; ++j) {
      zxv = fmaxf(zxv, zrow[h8 + j]);
      znv = fminf(znv, zrow[h8 + j]);
    }
    M -= (z == zxv) ? z : 0.f;
    N -= (z == znv) ? 1.f : 0.f;
  }

  const int base = n * FEATS + (DI * 4 + diff * 2) * 256 + tid;
  out[base]       = M > 0.f ? sqrtf(M) : 0.f;    // count_max
  out[base + 256] = N > 0.f ? sqrtf(N) : 0.f;    // count_min
}

// (256,3): per-wave register budget ~170 -> allocator can keep c + acc
// in arch VGPRs (no accvgpr round-trips), at 3 blocks/CU (issue-bound,
// occupancy loss irrelevant).
__global__ __launch_bounds__(256, 3) void hydra_kernel(
    const float* __restrict__ X, const float* __restrict__ W,
    float* __restrict__ out)
{
  __shared__ u32   xhl[XSZ];        // 16 KB packed bf16 hi|lo
  __shared__ float scratch[4096];   // 16 KB: 4 waves x [32][32]
  __shared__ float fin[512];        // 2 KB: [4][32][2]{M,N}
  switch (blockIdx.z) {
    case 0: body<1,   0>(X, W, out, xhl, scratch, fin); break;
    case 1: body<2,   1>(X, W, out, xhl, scratch, fin); break;
    case 2: body<4,   2>(X, W, out, xhl, scratch, fin); break;
    case 3: body<8,   3>(X, W, out, xhl, scratch, fin); break;
    case 4: body<16,  4>(X, W, out, xhl, scratch, fin); break;
    case 5: body<32,  5>(X, W, out, xhl, scratch, fin); break;
    case 6: body<64,  6>(X, W, out, xhl, scratch, fin); break;
    case 7: body<128, 7>(X, W, out, xhl, scratch, fin); break;
  }
}

} // namespace

extern "C" void kernel_launch(void* const* d_in, const int* in_sizes, int n_in,
                              void* d_out, int out_size, void* d_ws, size_t ws_size,
                              hipStream_t stream) {
  const float* X = (const float*)d_in[0];
  const float* W = (const float*)d_in[1];
  float* out = (float*)d_out;
  dim3 grid(NEX, 2, 8);
  hipLaunchKernelGGL(hydra_kernel, grid, dim3(256), 0, stream, X, W, out);
}

// Round 11
// 401.037 us; speedup vs baseline: 1.1698x; 1.0397x over previous
//
#include <hip/hip_runtime.h>
#include <math.h>

namespace {

typedef short short8 __attribute__((ext_vector_type(8)));
typedef float f32x16 __attribute__((ext_vector_type(16)));
typedef unsigned int u32;

constexpr int NEX = 256, LLEN = 2048, FEATS = 8192;
constexpr int PL = 512;          // 4*Dmax zeros on the left
constexpr int XSZ = 4096;
constexpr int BSTR = 17;         // bins stride: 16 bins + 1 pad word

// packed bf16 split: (lo_bf16 << 16) | hi_bf16, both RNE
__device__ __forceinline__ u32 bfsplit(float x) {
  u32 b = __float_as_uint(x);
  u32 hb = (b + 0x7fffu + ((b >> 16) & 1u)) >> 16;
  float lo = x - __uint_as_float(hb << 16);
  u32 b2 = __float_as_uint(lo);
  u32 lb = (b2 + 0x7fffu + ((b2 >> 16) & 1u)) >> 16;
  return hb | (lb << 16);
}

__device__ __forceinline__ float max8(const float* v, int o) {
  float m0 = fmaxf(fmaxf(v[o+0], v[o+1]), v[o+2]);
  float m1 = fmaxf(fmaxf(v[o+3], v[o+4]), v[o+5]);
  float m2 = fmaxf(v[o+6], v[o+7]);
  return fmaxf(fmaxf(m0, m1), m2);
}
__device__ __forceinline__ float min8(const float* v, int o) {
  float m0 = fminf(fminf(v[o+0], v[o+1]), v[o+2]);
  float m1 = fminf(fminf(v[o+3], v[o+4]), v[o+5]);
  float m2 = fminf(v[o+6], v[o+7]);
  return fminf(fminf(m0, m1), m2);
}

#define MFMA __builtin_amdgcn_mfma_f32_32x32x16_bf16

template<int D, int DI>
__device__ __forceinline__ void body(
    const float* __restrict__ X, const float* __restrict__ W,
    float* __restrict__ out, u32* __restrict__ xhl,
    float* __restrict__ binsM, float* __restrict__ binsN,
    float* __restrict__ fin)
{
  const int n = blockIdx.x, diff = blockIdx.y, tid = threadIdx.x;
  const int lane = tid & 63, wave = tid >> 6;
  const int col = lane & 31, hi = lane >> 5;

  // ---- stage padded input as packed bf16 hi/lo (diff on the fly) ----
  const float* xr = X + n * LLEN;
  for (int i = tid; i < XSZ; i += 256) {
    float x = 0.f;
    if (diff) { if (i >= PL && i < PL + LLEN - 1) x = xr[i - PL + 1] - xr[i - PL]; }
    else      { if (i >= PL && i < PL + LLEN)     x = xr[i - PL]; }
    xhl[i] = bfsplit(x);
  }

  // ---- lane-private bins (no barrier needed: wave-private region) ----
  float* myM = binsM + (wave * 64 + lane) * BSTR;
  float* myN = binsN + (wave * 64 + lane) * BSTR;
  #pragma unroll
  for (int b = 0; b < 16; ++b) { myM[b] = 0.f; myN[b] = 0.f; }
  __syncthreads();

  const float* wall = W + (DI * 2 + diff) * (256 * 9);

  // Permuted A-row -> kernel map: lane owns two complete 8-k groups.
  // row r holds kernel g*8+k, g = 2*(r>>4)+((r>>2)&1), k = (r&3)+4*((r>>3)&1).
  // acc index i of lane (col,hi) is local kern s = 8*hi + 16*(i>>3) + (i&7).
  const int g_of_r = ((col >> 4) << 1) | ((col >> 2) & 1);
  const int k_of_r = (col & 3) | (((col >> 3) & 1) << 2);
  const int kloc = g_of_r * 8 + k_of_r;

  const f32x16 czero = {};

  for (int kt2 = 0; kt2 < 2; ++kt2) {
    // A fragments for this 32-kern tile (taps padded 9->16 with zeros)
    short8 ah, al;
    {
      const float* wrow = wall + (wave * 64 + kt2 * 32 + kloc) * 9;
      #pragma unroll
      for (int e = 0; e < 8; ++e) {
        int j = hi * 8 + e;
        float wv = (j < 9) ? wrow[j] : 0.f;
        u32 p = bfsplit(wv);
        ah[e] = (short)(p & 0xffffu);
        al[e] = (short)(p >> 16);
      }
    }

    #pragma clang loop unroll_count(1)
    for (int tt = 0; tt < 64; ++tt) {
      // B fragment: B[j=8*hi+e][col] = x[tt*32 + col + (j-4)*D]
      const int ebase = PL + tt * 32 + col + (hi * 8 - 4) * D;
      u32 uu[8];
      #pragma unroll
      for (int e = 0; e < 8; ++e) uu[e] = xhl[ebase + e * D];
      union { short8 s; u32 u[4]; } bh, bl;
      #pragma unroll
      for (int p = 0; p < 4; ++p) {
        bh.u[p] = __builtin_amdgcn_perm(uu[2*p+1], uu[2*p], 0x05040100u);
        bl.u[p] = __builtin_amdgcn_perm(uu[2*p+1], uu[2*p], 0x07060302u);
      }

      // (wh+wl)(xh+xl) ~= wl*xh + wh*xl + wh*xh (lo*lo dropped)
      f32x16 c;
      c = MFMA(al, bh.s, czero, 0, 0, 0);
      c = MFMA(ah, bl.s, c,     0, 0, 0);
      c = MFMA(ah, bh.s, c,     0, 0, 0);

      // Embed k-index in low 4 mantissa bits: values become distinct,
      // max/min then carries its own argindex (error <= 16 ulp).
      float cf[16];
      #pragma unroll
      for (int i = 0; i < 16; ++i)
        cf[i] = __uint_as_float((__float_as_uint(c[i]) & 0xFFFFFFF0u) |
                                (u32)(i & 7));

      const float zx0 = max8(cf, 0), zn0 = min8(cf, 0);
      const float zx1 = max8(cf, 8), zn1 = min8(cf, 8);
      const u32 kx0 = __float_as_uint(zx0) & 15u;
      const u32 kn0 = __float_as_uint(zn0) & 15u;
      const u32 kx1 = __float_as_uint(zx1) & 15u;
      const u32 kn1 = __float_as_uint(zn1) & 15u;

      // Lane-private LDS bins: chunk0 -> bins 0..7, chunk1 -> bins 8..15.
      myM[kx0]     += zx0;
      myM[8 + kx1] += zx1;
      myN[kn0]     += 1.f;
      myN[8 + kn1] += 1.f;
    }

    // ---- flush: lanes 0..31 reduce M, lanes 32..63 reduce N ----
    // local kern s = 8*hi_s + 16*chunk + k lives at bin (chunk*8+k) of
    // lanes (col, hi_s), all col.
    {
      const int s = lane & 31;
      const int hi_s = (s >> 3) & 1;
      const int b = ((s >> 4) << 3) | (s & 7);
      const float* src =
          (lane < 32 ? binsM : binsN) + (wave * 64 + 32 * hi_s) * BSTR + b;
      float acc = 0.f;
      #pragma unroll
      for (int c2 = 0; c2 < 32; ++c2) acc += src[c2 * BSTR];
      fin[((wave * 32 + s) * 2 + kt2) * 2 + (lane >= 32 ? 1 : 0)] = acc;
    }

    // rezero own bins for next round (same-wave DS is in-order: safe)
    if (kt2 == 0) {
      #pragma unroll
      for (int b = 0; b < 16; ++b) { myM[b] = 0.f; myN[b] = 0.f; }
    }
  }
  __syncthreads();

  // ---- final: tid = kern (single owner) ----
  const int w2 = tid >> 6, kt2f = (tid >> 5) & 1, r = tid & 31;
  float M = fin[((w2 * 32 + r) * 2 + kt2f) * 2 + 0];
  float N = fin[((w2 * 32 + r) * 2 + kt2f) * 2 + 1];

  if (diff) {
    // remove the spurious t=2047 column (diff branch has 2047 timesteps)
    const float* wrow = wall + tid * 9;
    float z = 0.f;
    #pragma unroll
    for (int j = 0; j < 9; ++j) {
      u32 u = xhl[PL + (LLEN - 1) + (j - 4) * D];
      float xh = __uint_as_float((u & 0xffffu) << 16);
      float xl = __uint_as_float((u >> 16) << 16);
      u32 wp = bfsplit(wrow[j]);
      float wh = __uint_as_float((wp & 0xffffu) << 16);
      float wl = __uint_as_float((wp >> 16) << 16);
      z += wh * xh + wh * xl + wl * xh;
    }
    float* zrow = binsM;               // bins are dead now; reuse as scratch
    zrow[tid] = z;
    __syncthreads();
    const int h8 = tid & ~7;
    float zxv = zrow[h8], znv = zrow[h8];
    #pragma unroll
    for (int j = 1; j < 8; ++j) {
      zxv = fmaxf(zxv, zrow[h8 + j]);
      znv = fminf(znv, zrow[h8 + j]);
    }
    M -= (z == zxv) ? z : 0.f;
    N -= (z == znv) ? 1.f : 0.f;
  }

  const int base = n * FEATS + (DI * 4 + diff * 2) * 256 + tid;
  out[base]       = M > 0.f ? sqrtf(M) : 0.f;    // count_max
  out[base + 256] = N > 0.f ? sqrtf(N) : 0.f;    // count_min
}

__global__ __launch_bounds__(256, 3) void hydra_kernel(
    const float* __restrict__ X, const float* __restrict__ W,
    float* __restrict__ out)
{
  __shared__ u32   xhl[XSZ];                  // 16 KB packed bf16 hi|lo
  __shared__ float binsM[4 * 64 * BSTR];      // 17 KB lane-private max bins
  __shared__ float binsN[4 * 64 * BSTR];      // 17 KB lane-private min bins
  __shared__ float fin[1024];                 // 4 KB: [4][32][2]{M,N}
  switch (blockIdx.z) {
    case 0: body<1,   0>(X, W, out, xhl, binsM, binsN, fin); break;
    case 1: body<2,   1>(X, W, out, xhl, binsM, binsN, fin); break;
    case 2: body<4,   2>(X, W, out, xhl, binsM, binsN, fin); break;
    case 3: body<8,   3>(X, W, out, xhl, binsM, binsN, fin); break;
    case 4: body<16,  4>(X, W, out, xhl, binsM, binsN, fin); break;
    case 5: body<32,  5>(X, W, out, xhl, binsM, binsN, fin); break;
    case 6: body<64,  6>(X, W, out, xhl, binsM, binsN, fin); break;
    case 7: body<128, 7>(X, W, out, xhl, binsM, binsN, fin); break;
  }
}

} // namespace

extern "C" void kernel_launch(void* const* d_in, const int* in_sizes, int n_in,
                              void* d_out, int out_size, void* d_ws, size_t ws_size,
                              hipStream_t stream) {
  const float* X = (const float*)d_in[0];
  const float* W = (const float*)d_in[1];
  float* out = (float*)d_out;
  dim3 grid(NEX, 2, 8);
  hipLaunchKernelGGL(hydra_kernel, grid, dim3(256), 0, stream, X, W, out);
}